// Round 15
// baseline (157.977 us; speedup 1.0000x reference)
//
#include <hip/hip_runtime.h>

#define NB 8
#define CHW 6300
#define TT 500
#define OUT 128
#define NO 1024
#define NCC 50           // c-chunks of 128
#define PAD 32           // max indices kept per (n,t,chunk) segment

// ---------------- Kernel 1: transpose W[OUT][CHW] -> Wt[CHW][OUT] fp32 ----------------
__global__ __launch_bounds__(256) void packWt(const float* __restrict__ W,
                                              float* __restrict__ Wt) {
    __shared__ float tile[32][33];
    int bc = blockIdx.x * 32;
    int bo = blockIdx.y * 32;
    int tx = threadIdx.x;
    int ty = threadIdx.y;
#pragma unroll
    for (int k = 0; k < 4; k++) {
        int o = bo + ty + k * 8;
        int c = bc + tx;
        float v = (c < CHW) ? W[(size_t)o * CHW + c] : 0.f;
        tile[ty + k * 8][tx] = v;
    }
    __syncthreads();
#pragma unroll
    for (int k = 0; k < 4; k++) {
        int c = bc + ty + k * 8;
        int o = bo + tx;
        if (c < CHW) Wt[(size_t)c * OUT + o] = tile[tx][ty + k * 8];
    }
}

// ---------------- Kernel 2: LINEAR-read bitpack + index-list build ----------------
// Block (cc, n): owns c in [cc*128, +nc), ALL t. Phase 1: stream the block's
// x region with IDENTITY thread->address mapping (float4, fully linear, the
// session-wide fix for the ~2TB/s scattered-granule wall); nonzero lanes set
// bit (c&31) of LDS word bits[t][c>>5] via sparse atomicOr (~0.2 per float4).
// Phase 2: per t, emit c-ascending u16 index list (deterministic) + u8 count.
__global__ __launch_bounds__(256) void bitpackL(const float* __restrict__ x,
                                                unsigned short* __restrict__ xi,
                                                unsigned char* __restrict__ cnts) {
    const int cc = blockIdx.x;           // 0..49
    const int n  = blockIdx.y;           // 0..7
    const int tid = threadIdx.x;
    const int c0 = cc * 128;
    const int nc = min(128, CHW - c0);   // 128, last chunk 28

    __shared__ unsigned bits[TT][4];     // 8KB

    for (int i = tid; i < TT * 4; i += 256) ((unsigned*)bits)[i] = 0u;
    __syncthreads();

    const float4* xp = (const float4*)(x + ((size_t)n * CHW + c0) * TT);
    const int nf4 = nc * (TT / 4);       // float4s in this block's region

    for (int i = tid; i < nf4; i += 256) {
        float4 v = xp[i];
        int cl = i / 125;                // local c (TT/4 = 125 float4 per row)
        int t = (i - cl * 125) * 4;
        unsigned bit = 1u << (cl & 31);
        int w = cl >> 5;
        if (v.x != 0.f) atomicOr(&bits[t + 0][w], bit);
        if (v.y != 0.f) atomicOr(&bits[t + 1][w], bit);
        if (v.z != 0.f) atomicOr(&bits[t + 2][w], bit);
        if (v.w != 0.f) atomicOr(&bits[t + 3][w], bit);
    }
    __syncthreads();

    for (int t = tid; t < TT; t += 256) {
        const size_t seg = (size_t)(n * TT + t) * NCC + cc;
        unsigned short* op = xi + seg * PAD;
        int cnt = 0;
#pragma unroll
        for (int w = 0; w < 4; ++w) {
            unsigned wv = bits[t][w];
            while (wv) {
                int b = __builtin_ctz(wv);
                wv &= wv - 1;
                if (cnt < PAD) op[cnt] = (unsigned short)(c0 + w * 32 + b);
                cnt++;
            }
        }
        cnts[seg] = (unsigned char)min(cnt, PAD);
    }
}

// ---------------- Kernel 3: index-driven sparse projection ----------------
// 4 waves/block, wave = one (n,t). Per segment: count from LDS (broadcast),
// indices via UNIFORM uint4 loads (8 u16 each, no shfl chain), then 8
// independent coalesced 512B W-row float2 loads -> fp32 adds (exact, x=1).
__global__ __launch_bounds__(256) void spgemmI(const unsigned short* __restrict__ xi,
                                               const unsigned char* __restrict__ cnts,
                                               const float* __restrict__ Wt,
                                               float* __restrict__ vred) {
    const int tid = threadIdx.x;
    const int wv = tid >> 6;
    const int lane = tid & 63;
    const int nt = blockIdx.x * 4 + wv;      // 0..3999
    const int n = nt / TT;
    const int t = nt - n * TT;

    __shared__ unsigned char cwl[4][NCC];

    if (tid < 4 * NCC)
        ((unsigned char*)cwl)[tid] = cnts[(size_t)blockIdx.x * 4 * NCC + tid];
    __syncthreads();

    const uint4* ip = (const uint4*)(xi + (size_t)nt * NCC * PAD);  // 4 uint4/seg
    const float2* Wp2 = (const float2*)Wt;

    float aA0 = 0.f, aA1 = 0.f, aB0 = 0.f, aB1 = 0.f;

    for (int s = 0; s < NCC; ++s) {
        const int k = cwl[wv][s];
        if (k == 0) continue;
#pragma unroll
        for (int g = 0; g < 4; ++g) {
            if (g * 8 < k) {
                uint4 iv = ip[s * 4 + g];     // uniform: 8 u16 indices
                const unsigned iw[4] = {iv.x, iv.y, iv.z, iv.w};
#pragma unroll
                for (int i = 0; i < 8; ++i) {
                    if (g * 8 + i < k) {      // uniform (k scalar) -> cheap
                        int c = (iw[i >> 1] >> ((i & 1) * 16)) & 0xffff;
                        float2 w = Wp2[(size_t)c * 64 + lane];
                        if (i & 1) { aB0 += w.x; aB1 += w.y; }
                        else       { aA0 += w.x; aA1 += w.y; }
                    }
                }
            }
        }
    }

    float r0 = aA0 + aB0;
    float r1 = aA1 + aB1;
    *(float2*)(vred + ((size_t)t * NB + n) * OUT + lane * 2) = make_float2(r0, r1);
}

// ---------------- Kernel 4: wave-specialized alpha+spike scan ----------------
// 32 blocks x 512 thr, 32 chains/block. Wave 0 (lanes 0-31): serial G/H
// recursion; waves 1-7: stage next vred slab into vbuf[t][chain].
#define SCN_RA 0.9048374180359595f       // exp(-0.1)
#define SCN_RACA 0.24596031111569496f    // RA*CA = 0.1*e^0.9
#define SCN_RS 0.36787944117144233f      // exp(-1)
#define SCN_RSCS -20.0f                  // RS*CS (CS = -20e)
#define SCN_RSCS2 -40.0f                 // 2*RS*CS
#define SCN_RSRSCS -7.3575888234288467f  // RS*RS*CS
#define SCN_TH 10.0f

#define CHAIN_STEP(i)                                                   \
    {                                                                   \
        float ua = Aa;                                                  \
        float w = fmaf(SCN_RS, G, ua);                                  \
        float u = sp ? (w + SCN_RSCS) : w;                              \
        bool sn = (u >= SCN_TH);                                        \
        sbuf[i][lane] = sn ? 1.f : 0.f;                                 \
        float Gb = fmaf(SCN_RS, G, H);                                  \
        G = sp ? (Gb + SCN_RSCS2) : Gb;                                 \
        float Hb = SCN_RS * H;                                          \
        H = sp ? (Hb + SCN_RSRSCS) : Hb;                                \
        sp = sn;                                                        \
        Ba = fmaf(SCN_RA, Ba, SCN_RACA * vv[i]);                        \
        Aa = fmaf(SCN_RA, Aa, Ba);                                      \
    }

__global__ __launch_bounds__(512) void scanspike(const float* __restrict__ vred,
                                                 float* __restrict__ out) {
    const int tid = threadIdx.x;
    const int wave = tid >> 6;
    const int lane = tid & 63;
    const int l5 = lane & 31;
    const int rh = lane >> 5;
    const int g0 = blockIdx.x * 32;
    const int cn = g0 >> 7;
    const int co = (g0 & 127) + l5;

    __shared__ float vbuf[2][64][32];
    __shared__ float sbuf[64][33];

    for (int rp = wave; rp * 2 < 64; rp += 8) {
        int r = rp * 2 + rh;
        vbuf[0][r][l5] = vred[((size_t)r * NB + cn) * OUT + co];
    }
    __syncthreads();

    float Aa = 0.f, Ba = 0.f, G = 0.f, H = 0.f;
    bool sp = false;

    for (int tb = 0; tb < 8; ++tb) {
        const int cur = tb & 1;
        const int t0 = tb * 64;
        const int cnt = (tb == 7) ? 52 : 64;

        if (wave == 0) {
            if (lane < 32) {
                if (cnt == 64) {
                    float vv[64];
#pragma unroll
                    for (int i = 0; i < 64; ++i) vv[i] = vbuf[cur][i][l5];
#pragma unroll
                    for (int i = 0; i < 64; ++i) CHAIN_STEP(i)
                } else {
                    float vv[52];
#pragma unroll
                    for (int i = 0; i < 52; ++i) vv[i] = vbuf[cur][i][l5];
#pragma unroll
                    for (int i = 0; i < 52; ++i) CHAIN_STEP(i)
                }
            }
        } else if (tb < 7) {
            const int nt0 = t0 + 64;
            const int ncnt = (tb == 6) ? 52 : 64;
            for (int rp = wave - 1; rp * 2 < ncnt; rp += 7) {
                int r = rp * 2 + rh;
                vbuf[cur ^ 1][r][l5] = vred[((size_t)(nt0 + r) * NB + cn) * OUT + co];
            }
        }
        __syncthreads();

#pragma unroll
        for (int j = 0; j < 4; ++j) {
            int cc = wave * 4 + j;
            int oo = (g0 & 127) + cc;
            if (lane < cnt)
                out[((size_t)cn * OUT + oo) * TT + t0 + lane] = sbuf[lane][cc];
        }
        __syncthreads();
    }
}

extern "C" void kernel_launch(void* const* d_in, const int* in_sizes, int n_in,
                              void* d_out, int out_size, void* d_ws, size_t ws_size,
                              hipStream_t stream) {
    const float* x = (const float*)d_in[0];   // [8,2,50,63,500] fp32
    const float* W = (const float*)d_in[1];   // [128,6300] fp32
    float* out = (float*)d_out;               // [8,128,1,1,500] fp32

    float*          Wt   = (float*)d_ws;                               //  3,225,600 B
    unsigned short* xi   = (unsigned short*)((char*)d_ws + 3225600);   // 12,800,000 B
    unsigned char*  cnts = (unsigned char*)((char*)d_ws + 16025600);   //    200,064 B
    float*          vred = (float*)((char*)d_ws + 16225664);           //  2,048,000 B

    packWt<<<dim3((CHW + 31) / 32, OUT / 32), dim3(32, 8), 0, stream>>>(W, Wt);
    bitpackL<<<dim3(NCC, NB), 256, 0, stream>>>(x, xi, cnts);
    spgemmI<<<1000, 256, 0, stream>>>(xi, cnts, Wt, vred);
    scanspike<<<32, 512, 0, stream>>>(vred, out);
}

// Round 16
// 100.736 us; speedup vs baseline: 1.5682x; 1.5682x over previous
//
#include <hip/hip_runtime.h>

#define NB 8
#define CHW 6300
#define TT 500
#define OUT 128
#define NO 1024
#define NK32 200          // k32 chunks (c padded to 6400)
#define KSPLIT 8
#define NKC (NK32/KSPLIT) // 25 k32 per ks

typedef __attribute__((ext_vector_type(8))) _Float16 f16x8;
typedef __attribute__((ext_vector_type(4))) float f32x4;

// ---------------- Kernel 1: pack W into MFMA A-fragment order ----------------
// Wp[hl][k32][of][lane][8]; o=of*16+(lane&15), c=k32*32+(lane>>4)*8+i
// hl=0: f16(W); hl=1: f16((W - f16(W)) * 2048). Zero-padded for c>=CHW.
__global__ __launch_bounds__(512) void packW(const float* __restrict__ W,
                                             _Float16* __restrict__ Wp) {
    const int tid = threadIdx.x;
    const int of = tid >> 6;
    const int lane = tid & 63;
    const int k32 = blockIdx.x;
    const int hl = blockIdx.y;
    const int o = of * 16 + (lane & 15);
    const int cb = k32 * 32 + (lane >> 4) * 8;

    union { _Float16 h[8]; uint4 u; } tmp;
#pragma unroll
    for (int i = 0; i < 8; i++) {
        int c = cb + i;
        float w = (c < CHW) ? W[(size_t)o * CHW + c] : 0.f;
        _Float16 hi = (_Float16)w;
        tmp.h[i] = (hl == 0) ? hi : (_Float16)((w - (float)hi) * 2048.f);
    }
    size_t lr = (((size_t)hl * NK32 + k32) * 8 + of) * 64 + lane;
    *(uint4*)(Wp + lr * 8) = tmp.u;
}

// ---------------- Kernel 2: pure-linear x ingest + chunk transpose ----------------
// Block (k32, n): reads 32 c-rows = 64KB FULLY CONTIGUOUS (float4, identity
// mapping), converts f16 into LDS, then writes xT2[n][k32][t][32c] = 32KB
// CONTIGUOUS. Measures the true x streaming ceiling; big granules both sides.
__global__ __launch_bounds__(256) void xstage(const float* __restrict__ x,
                                              _Float16* __restrict__ xT2) {
    const int k32 = blockIdx.x;           // 0..199
    const int n   = blockIdx.y;
    const int tid = threadIdx.x;
    const int c0  = k32 * 32;
    const int nc  = min(32, CHW - c0);    // 32 | 28 | <=0 (padding)

    __shared__ _Float16 Xs[32][500];      // 31.25KB

    if (nc < 32) {
        for (int i = tid; i < 32 * 250; i += 256)
            ((unsigned*)&Xs[0][0])[i] = 0u;
        __syncthreads();                  // block-uniform branch
    }
    if (nc > 0) {
        const float4* xr = (const float4*)(x + ((size_t)n * CHW + c0) * TT);
        const int nf4 = nc * 125;         // float4s in region
        for (int i = tid; i < nf4; i += 256) {
            float4 v = xr[i];
            int cl = i / 125;
            int tl = (i - cl * 125) * 4;
            union { _Float16 h[4]; uint2 u; } pk;
            pk.h[0] = (_Float16)v.x; pk.h[1] = (_Float16)v.y;
            pk.h[2] = (_Float16)v.z; pk.h[3] = (_Float16)v.w;
            *(uint2*)&Xs[cl][tl] = pk.u;
        }
    }
    __syncthreads();

    _Float16* op = xT2 + ((size_t)(n * NK32 + k32) * TT) * 32;
    for (int t = tid; t < TT; t += 256) {
        union { _Float16 h[32]; uint4 q[4]; } row;
#pragma unroll
        for (int c = 0; c < 32; ++c) row.h[c] = Xs[c][t];
        uint4* dst = (uint4*)(op + (size_t)t * 32);
        dst[0] = row.q[0]; dst[1] = row.q[1];
        dst[2] = row.q[2]; dst[3] = row.q[3];
    }
}

// ---------------- Kernel 3: zero-LDS zero-barrier MFMA GEMM ----------------
// B-frags load DIRECTLY from xT2 (chunk layout == fragment order: one uint4
// per lane, 1KB contiguous per instruction). A-frags reg-double-buffered from
// Wp (L2-resident). Per wave: 16t x 64o x (K/8); no LDS, no barriers.
__global__ __launch_bounds__(256, 2) void gemm(const _Float16* __restrict__ xT2,
                                               const _Float16* __restrict__ Wp,
                                               float* __restrict__ vp) {
    const int L = blockIdx.x;            // 0..1023
    const int ks = L & 7;                // XCD-affine k-split
    const int n  = (L >> 3) & 7;
    const int tt = L >> 6;               // 0..15
    const int tid = threadIdx.x;
    const int wave = tid >> 6;
    const int lane = tid & 63;
    const int l15 = lane & 15;
    const int lg  = lane >> 4;
    const int th = wave & 1;             // t half
    const int oh = wave >> 1;            // o half
    const int t0 = tt * 32 + th * 16;
    const int k32_0 = ks * NKC;

    const _Float16* bbase = xT2 +
        (((size_t)n * NK32 + k32_0) * TT + t0) * 32 + l15 * 32 + lg * 8;

    f32x4 acc[4][2] = {};                // [of][hl]
    f16x8 a0[8], a1[8];                  // A frag dbuf [of*2+hl]
    uint4 b0, b1;                        // B frag dbuf

#define BLD(bv, it_) bv = *(const uint4*)(bbase + (size_t)(it_) * (TT * 32));
#define ALD(av, it_)                                                           \
    _Pragma("unroll") for (int f_ = 0; f_ < 8; f_++) {                         \
        const int hl_ = f_ & 1, of_ = f_ >> 1;                                 \
        av[f_] = *(const f16x8*)(Wp +                                          \
            ((((size_t)hl_ * NK32 + k32_0 + (it_)) * 8 + oh * 4 + of_) * 64 +  \
             lane) * 8);                                                       \
    }
#define CMP(av, bv)                                                            \
    {                                                                          \
        f16x8 bf = *(const f16x8*)&bv;                                         \
        _Pragma("unroll") for (int of_ = 0; of_ < 4; of_++)                    \
            _Pragma("unroll") for (int hl_ = 0; hl_ < 2; hl_++)                \
                acc[of_][hl_] = __builtin_amdgcn_mfma_f32_16x16x32_f16(        \
                    av[of_ * 2 + hl_], bf, acc[of_][hl_], 0, 0, 0);            \
    }

    ALD(a0, 0) BLD(b0, 0)
    for (int p = 0; p < 12; ++p) {
        ALD(a1, 2 * p + 1) BLD(b1, 2 * p + 1)
        CMP(a0, b0)
        ALD(a0, 2 * p + 2) BLD(b0, 2 * p + 2)
        CMP(a1, b1)
    }
    CMP(a0, b0)                          // it = 24

    const float inv = 1.f / 2048.f;
    const int t = t0 + l15;
    if (t < TT) {
#pragma unroll
        for (int of = 0; of < 4; of++) {
            f32x4 vo;
#pragma unroll
            for (int r = 0; r < 4; r++)
                vo[r] = acc[of][0][r] + acc[of][1][r] * inv;
            *(f32x4*)(vp + (((size_t)ks * TT + t) * NB + n) * OUT +
                      (oh * 4 + of) * 16 + lg * 4) = vo;
        }
    }
#undef BLD
#undef ALD
#undef CMP
}

// ---------------- Kernel 4: wave-specialized alpha+spike scan, fused 8-partial ----
// 32 blocks x 512 thr, 32 chains/block. Wave 0 (lanes 0-31): serial G/H
// recursion; waves 1-7: stage next slab with 8-partial K-sum fused (fixed order).
#define SCN_RA 0.9048374180359595f       // exp(-0.1)
#define SCN_RACA 0.24596031111569496f    // RA*CA = 0.1*e^0.9
#define SCN_RS 0.36787944117144233f      // exp(-1)
#define SCN_RSCS -20.0f                  // RS*CS (CS = -20e)
#define SCN_RSCS2 -40.0f                 // 2*RS*CS
#define SCN_RSRSCS -7.3575888234288467f  // RS*RS*CS
#define SCN_TH 10.0f

#define CHAIN_STEP(i)                                                   \
    {                                                                   \
        float ua = Aa;                                                  \
        float w = fmaf(SCN_RS, G, ua);                                  \
        float u = sp ? (w + SCN_RSCS) : w;                              \
        bool sn = (u >= SCN_TH);                                        \
        sbuf[i][lane] = sn ? 1.f : 0.f;                                 \
        float Gb = fmaf(SCN_RS, G, H);                                  \
        G = sp ? (Gb + SCN_RSCS2) : Gb;                                 \
        float Hb = SCN_RS * H;                                          \
        H = sp ? (Hb + SCN_RSRSCS) : Hb;                                \
        sp = sn;                                                        \
        Ba = fmaf(SCN_RA, Ba, SCN_RACA * vv[i]);                        \
        Aa = fmaf(SCN_RA, Aa, Ba);                                      \
    }

__global__ __launch_bounds__(512) void scanspike(const float* __restrict__ vp,
                                                 float* __restrict__ out) {
    const int tid = threadIdx.x;
    const int wave = tid >> 6;
    const int lane = tid & 63;
    const int l5 = lane & 31;
    const int rh = lane >> 5;
    const int g0 = blockIdx.x * 32;
    const int cn = g0 >> 7;
    const int co = (g0 & 127) + l5;

    __shared__ float vbuf[2][64][32];
    __shared__ float sbuf[64][33];

    for (int rp = wave; rp * 2 < 64; rp += 8) {
        int r = rp * 2 + rh;
        float a = 0.f;
#pragma unroll
        for (int k = 0; k < KSPLIT; k++)
            a += vp[(((size_t)k * TT + r) * NB + cn) * OUT + co];
        vbuf[0][r][l5] = a;
    }
    __syncthreads();

    float Aa = 0.f, Ba = 0.f, G = 0.f, H = 0.f;
    bool sp = false;

    for (int tb = 0; tb < 8; ++tb) {
        const int cur = tb & 1;
        const int t0 = tb * 64;
        const int cnt = (tb == 7) ? 52 : 64;

        if (wave == 0) {
            if (lane < 32) {
                if (cnt == 64) {
                    float vv[64];
#pragma unroll
                    for (int i = 0; i < 64; ++i) vv[i] = vbuf[cur][i][l5];
#pragma unroll
                    for (int i = 0; i < 64; ++i) CHAIN_STEP(i)
                } else {
                    float vv[52];
#pragma unroll
                    for (int i = 0; i < 52; ++i) vv[i] = vbuf[cur][i][l5];
#pragma unroll
                    for (int i = 0; i < 52; ++i) CHAIN_STEP(i)
                }
            }
        } else if (tb < 7) {
            const int nt0 = t0 + 64;
            const int ncnt = (tb == 6) ? 52 : 64;
            for (int rp = wave - 1; rp * 2 < ncnt; rp += 7) {
                int r = rp * 2 + rh;
                float a = 0.f;
#pragma unroll
                for (int k = 0; k < KSPLIT; k++)
                    a += vp[(((size_t)k * TT + nt0 + r) * NB + cn) * OUT + co];
                vbuf[cur ^ 1][r][l5] = a;
            }
        }
        __syncthreads();

#pragma unroll
        for (int j = 0; j < 4; ++j) {
            int cc = wave * 4 + j;
            int oo = (g0 & 127) + cc;
            if (lane < cnt)
                out[((size_t)cn * OUT + oo) * TT + t0 + lane] = sbuf[lane][cc];
        }
        __syncthreads();
    }
}

extern "C" void kernel_launch(void* const* d_in, const int* in_sizes, int n_in,
                              void* d_out, int out_size, void* d_ws, size_t ws_size,
                              hipStream_t stream) {
    const float* x = (const float*)d_in[0];   // [8,2,50,63,500] fp32
    const float* W = (const float*)d_in[1];   // [128,6300] fp32
    float* out = (float*)d_out;               // [8,128,1,1,500] fp32

    _Float16* Wp  = (_Float16*)d_ws;                          //  3,276,800 B
    _Float16* xT2 = (_Float16*)((char*)d_ws + 3276800);       // 51,200,000 B (+4KB pad)
    float*    vp  = (float*)((char*)d_ws + 3276800 + 51204096);  // 16,384,000 B

    packW<<<dim3(NK32, 2), 512, 0, stream>>>(W, Wp);
    xstage<<<dim3(NK32, NB), 256, 0, stream>>>(x, xT2);
    gemm<<<1024, 256, 0, stream>>>(xT2, Wp, vp);
    scanspike<<<32, 512, 0, stream>>>(vp, out);
}

// Round 17
// 86.853 us; speedup vs baseline: 1.8189x; 1.1598x over previous
//
#include <hip/hip_runtime.h>

#define NB 8
#define CHW 6300
#define TT 500
#define OUT 128
#define NO 1024
#define NK32 200          // k32 chunks (c padded to 6400)
#define KSPLIT 8
#define NKC (NK32/KSPLIT) // 25 k32 per ks
#define CPAD 6400

typedef __attribute__((ext_vector_type(8))) _Float16 f16x8;
typedef __attribute__((ext_vector_type(4))) float f32x4;
typedef unsigned long long u64;

// ---------------- Kernel 1: pack W into MFMA A-fragment order ----------------
// Wp[hl][k32][of][lane][8]; o=of*16+(lane&15), c=k32*32+(lane>>4)*8+i
// hl=0: f16(W); hl=1: f16((W - f16(W)) * 2048). Zero-padded for c>=CHW.
__global__ __launch_bounds__(512) void packW(const float* __restrict__ W,
                                             _Float16* __restrict__ Wp) {
    const int tid = threadIdx.x;
    const int of = tid >> 6;
    const int lane = tid & 63;
    const int k32 = blockIdx.x;
    const int hl = blockIdx.y;
    const int o = of * 16 + (lane & 15);
    const int cb = k32 * 32 + (lane >> 4) * 8;

    union { _Float16 h[8]; uint4 u; } tmp;
#pragma unroll
    for (int i = 0; i < 8; i++) {
        int c = cb + i;
        float w = (c < CHW) ? W[(size_t)o * CHW + c] : 0.f;
        _Float16 hi = (_Float16)w;
        tmp.h[i] = (hl == 0) ? hi : (_Float16)((w - (float)hi) * 2048.f);
    }
    size_t lr = (((size_t)hl * NK32 + k32) * 8 + of) * 64 + lane;
    *(uint4*)(Wp + lr * 8) = tmp.u;
}

// ---------------- Kernel 2: ballot bitpack — the transpose IS the ballot ----------------
// Block (cc,n): c in [cc*32, +32), all t. Wave task (c, tg): 64 lanes load 64
// consecutive t (256B granule), __ballot(v!=0) -> u64 of t-bits, lane 0 stores.
// 64 fully-independent loads per thread, unroll 8 -> deep MLP; read-only 100MB
// stream, 3.2MB writes, no LDS. Every xb word is written (no stale ws reads).
__global__ __launch_bounds__(256) void bitpack(const float* __restrict__ x,
                                               u64* __restrict__ xb) {
    const int cc = blockIdx.x;        // 0..199
    const int n  = blockIdx.y;        // 0..7
    const int tid = threadIdx.x;
    const int wv = tid >> 6;
    const int lane = tid & 63;
    const int c0 = cc * 32;
    const float* xn = x + (size_t)n * CHW * TT;
    u64* xbn = xb + (size_t)n * 8 * CPAD;

#pragma unroll 8
    for (int task = wv; task < 256; task += 4) {
        const int cl = task >> 3;
        const int tg = task & 7;
        const int c = c0 + cl;
        const int t = tg * 64 + lane;
        float v = (c < CHW && t < TT) ? xn[(size_t)c * TT + t] : 0.f;
        u64 m = __ballot(v != 0.f);
        if (lane == 0) xbn[(size_t)tg * CPAD + c] = m;
    }
}

// ---------------- Kernel 3: bit-expanding MFMA GEMM ----------------
// Block (tg,n,ks): 64t x 128o x 800c. Bit-slab (800 u64 = 6.4KB) staged to LDS
// once (ONE barrier total). Per k32 step: 8 u64 broadcast ds-reads, expand to
// 4 t-frags of f16 {0,1} in-register (~112 VALU), 16 MFMA; W A-frags
// register-double-buffered from Wp (L2). No other barriers, no x traffic.
__global__ __launch_bounds__(256, 2) void gemm(const u64* __restrict__ xb,
                                               const _Float16* __restrict__ Wp,
                                               float* __restrict__ vp) {
    const int L = blockIdx.x;        // 0..511
    const int ks = L & 7;            // XCD-affine
    const int n  = (L >> 3) & 7;
    const int tg = L >> 6;           // 0..7 (64 t each)
    const int tid = threadIdx.x;
    const int w = tid >> 6;          // wave: ofrags {2w, 2w+1}
    const int lane = tid & 63;
    const int l15 = lane & 15;
    const int lg  = lane >> 4;
    const int k32_0 = ks * NKC;

    __shared__ u64 Bits[NKC * 32];   // 6.4KB

    {
        const u64* src = xb + ((size_t)n * 8 + tg) * CPAD + ks * (NKC * 32);
        for (int i = tid; i < NKC * 32; i += 256) Bits[i] = src[i];
    }
    __syncthreads();

    f32x4 acc[2][4][2] = {};         // [of][tf][hl]
    f16x8 wA[4], wB[4];              // W frag dbuf [of*2+hl]

#define WLD(wd, it_)                                                           \
    _Pragma("unroll") for (int f_ = 0; f_ < 4; f_++) {                         \
        const int hl_ = f_ & 1, of_ = f_ >> 1;                                 \
        wd[f_] = *(const f16x8*)(Wp +                                          \
            ((((size_t)hl_ * NK32 + k32_0 + (it_)) * 8 + w * 2 + of_) * 64 +   \
             lane) * 8);                                                       \
    }

// expand + 16 MFMA for step it_ using W regs wd
#define STEP(it_, wd)                                                          \
    {                                                                          \
        unsigned hlo_[8], hhi_[8];                                             \
        _Pragma("unroll") for (int i_ = 0; i_ < 8; i_++) {                     \
            u64 bw_ = Bits[(it_) * 32 + lg * 8 + i_];                          \
            hlo_[i_] = (unsigned)bw_;                                          \
            hhi_[i_] = (unsigned)(bw_ >> 32);                                  \
        }                                                                      \
        _Pragma("unroll") for (int tf_ = 0; tf_ < 4; tf_++) {                  \
            union { unsigned u[4]; f16x8 v; } bu_;                             \
            const int sh_ = ((tf_) & 1) * 16 + l15;                            \
            _Pragma("unroll") for (int j_ = 0; j_ < 4; j_++) {                 \
                unsigned b0_ = (((tf_) < 2 ? hlo_[2 * j_] : hhi_[2 * j_])      \
                                >> sh_) & 1u;                                  \
                unsigned b1_ = (((tf_) < 2 ? hlo_[2 * j_ + 1] : hhi_[2 * j_ + 1]) \
                                >> sh_) & 1u;                                  \
                bu_.u[j_] = (b0_ ? 0x3C00u : 0u) | (b1_ ? 0x3C000000u : 0u);   \
            }                                                                  \
            _Pragma("unroll") for (int of_ = 0; of_ < 2; of_++)                \
                _Pragma("unroll") for (int hl_ = 0; hl_ < 2; hl_++)            \
                    acc[of_][tf_][hl_] = __builtin_amdgcn_mfma_f32_16x16x32_f16( \
                        wd[of_ * 2 + hl_], bu_.v, acc[of_][tf_][hl_], 0, 0, 0); \
        }                                                                      \
    }

    WLD(wA, 0)
    for (int p = 0; p < 12; ++p) {
        WLD(wB, 2 * p + 1)
        STEP(2 * p, wA)
        WLD(wA, 2 * p + 2)
        STEP(2 * p + 1, wB)
    }
    STEP(24, wA)                     // it = 24

    // epilogue: D col(l15)=t, row=lg*4+r=o; combine hi/lo
    const float inv = 1.f / 2048.f;
#pragma unroll
    for (int of = 0; of < 2; of++) {
#pragma unroll
        for (int tf = 0; tf < 4; tf++) {
            const int t = tg * 64 + tf * 16 + l15;
            if (t < TT) {
                f32x4 vo;
#pragma unroll
                for (int r = 0; r < 4; r++)
                    vo[r] = acc[of][tf][0][r] + acc[of][tf][1][r] * inv;
                *(f32x4*)(vp + (((size_t)ks * TT + t) * NB + n) * OUT +
                          (w * 2 + of) * 16 + lg * 4) = vo;
            }
        }
    }
#undef WLD
#undef STEP
}

// ---------------- Kernel 4: wave-specialized alpha+spike scan, fused 8-partial ----
#define SCN_RA 0.9048374180359595f       // exp(-0.1)
#define SCN_RACA 0.24596031111569496f    // RA*CA = 0.1*e^0.9
#define SCN_RS 0.36787944117144233f      // exp(-1)
#define SCN_RSCS -20.0f                  // RS*CS (CS = -20e)
#define SCN_RSCS2 -40.0f                 // 2*RS*CS
#define SCN_RSRSCS -7.3575888234288467f  // RS*RS*CS
#define SCN_TH 10.0f

#define CHAIN_STEP(i)                                                   \
    {                                                                   \
        float ua = Aa;                                                  \
        float w = fmaf(SCN_RS, G, ua);                                  \
        float u = sp ? (w + SCN_RSCS) : w;                              \
        bool sn = (u >= SCN_TH);                                        \
        sbuf[i][lane] = sn ? 1.f : 0.f;                                 \
        float Gb = fmaf(SCN_RS, G, H);                                  \
        G = sp ? (Gb + SCN_RSCS2) : Gb;                                 \
        float Hb = SCN_RS * H;                                          \
        H = sp ? (Hb + SCN_RSRSCS) : Hb;                                \
        sp = sn;                                                        \
        Ba = fmaf(SCN_RA, Ba, SCN_RACA * vv[i]);                        \
        Aa = fmaf(SCN_RA, Aa, Ba);                                      \
    }

__global__ __launch_bounds__(512) void scanspike(const float* __restrict__ vp,
                                                 float* __restrict__ out) {
    const int tid = threadIdx.x;
    const int wave = tid >> 6;
    const int lane = tid & 63;
    const int l5 = lane & 31;
    const int rh = lane >> 5;
    const int g0 = blockIdx.x * 32;
    const int cn = g0 >> 7;
    const int co = (g0 & 127) + l5;

    __shared__ float vbuf[2][64][32];
    __shared__ float sbuf[64][33];

    for (int rp = wave; rp * 2 < 64; rp += 8) {
        int r = rp * 2 + rh;
        float a = 0.f;
#pragma unroll
        for (int k = 0; k < KSPLIT; k++)
            a += vp[(((size_t)k * TT + r) * NB + cn) * OUT + co];
        vbuf[0][r][l5] = a;
    }
    __syncthreads();

    float Aa = 0.f, Ba = 0.f, G = 0.f, H = 0.f;
    bool sp = false;

    for (int tb = 0; tb < 8; ++tb) {
        const int cur = tb & 1;
        const int t0 = tb * 64;
        const int cnt = (tb == 7) ? 52 : 64;

        if (wave == 0) {
            if (lane < 32) {
                if (cnt == 64) {
                    float vv[64];
#pragma unroll
                    for (int i = 0; i < 64; ++i) vv[i] = vbuf[cur][i][l5];
#pragma unroll
                    for (int i = 0; i < 64; ++i) CHAIN_STEP(i)
                } else {
                    float vv[52];
#pragma unroll
                    for (int i = 0; i < 52; ++i) vv[i] = vbuf[cur][i][l5];
#pragma unroll
                    for (int i = 0; i < 52; ++i) CHAIN_STEP(i)
                }
            }
        } else if (tb < 7) {
            const int nt0 = t0 + 64;
            const int ncnt = (tb == 6) ? 52 : 64;
            for (int rp = wave - 1; rp * 2 < ncnt; rp += 7) {
                int r = rp * 2 + rh;
                float a = 0.f;
#pragma unroll
                for (int k = 0; k < KSPLIT; k++)
                    a += vp[(((size_t)k * TT + nt0 + r) * NB + cn) * OUT + co];
                vbuf[cur ^ 1][r][l5] = a;
            }
        }
        __syncthreads();

#pragma unroll
        for (int j = 0; j < 4; ++j) {
            int cc = wave * 4 + j;
            int oo = (g0 & 127) + cc;
            if (lane < cnt)
                out[((size_t)cn * OUT + oo) * TT + t0 + lane] = sbuf[lane][cc];
        }
        __syncthreads();
    }
}

extern "C" void kernel_launch(void* const* d_in, const int* in_sizes, int n_in,
                              void* d_out, int out_size, void* d_ws, size_t ws_size,
                              hipStream_t stream) {
    const float* x = (const float*)d_in[0];   // [8,2,50,63,500] fp32
    const float* W = (const float*)d_in[1];   // [128,6300] fp32
    float* out = (float*)d_out;               // [8,128,1,1,500] fp32

    _Float16* Wp = (_Float16*)d_ws;                      //  3,276,800 B
    u64*      xb = (u64*)((char*)d_ws + 3276800);        //  3,276,800 B
    float*    vp = (float*)((char*)d_ws + 6553600);      // 16,384,000 B

    packW<<<dim3(NK32, 2), 512, 0, stream>>>(W, Wp);
    bitpack<<<dim3(NK32, NB), 256, 0, stream>>>(x, xb);
    gemm<<<512, 256, 0, stream>>>(xb, Wp, vp);
    scanspike<<<32, 512, 0, stream>>>(vp, out);
}

// Round 18
// 71.619 us; speedup vs baseline: 2.2058x; 1.2127x over previous
//
#include <hip/hip_runtime.h>

#define NB 8
#define CHW 6300
#define TT 500
#define OUT 128
#define NO 1024
#define NK32 200          // total k32 steps (padded: 6300 -> 6400)
#define KSPLIT 8
#define NKC (NK32/KSPLIT) // 25 k32 per block

typedef __attribute__((ext_vector_type(8))) _Float16 f16x8;
typedef __attribute__((ext_vector_type(4))) float f32x4;

// Raw workgroup barrier draining ONLY lgkmcnt (LDS writes), not vmcnt:
// keeps global-load prefetches in flight across the barrier.
__device__ __forceinline__ void wg_barrier_lgkm() {
    asm volatile("s_waitcnt lgkmcnt(0)" ::: "memory");
    __builtin_amdgcn_s_barrier();
}

// ---------------- Kernel 1: fused pack+transpose+convert+MFMA GEMM ----------------
// R10 structure restored verbatim (best: 58.3us). ONE change: x loads are
// NON-TEMPORAL (nt flag) — the 100MB x stream is single-use; bypassing L2/L3
// allocation removes cache-thrash on the only binding resource (x-read BW).
__global__ __launch_bounds__(256, 2) void gemm(const float* __restrict__ x,
                                               const float* __restrict__ W,
                                               float* __restrict__ vp) {
    const int L = blockIdx.x;                 // 0..511
    const int logical = (L & 7) * 64 + (L >> 3);
    const int tb = logical & 7;               // t-block (64 t)
    const int n  = (logical >> 3) & 7;        // batch
    const int ks = logical >> 6;              // k-split 0..7

    const int tid = threadIdx.x;
    const int wave = tid >> 6;
    const int lane = tid & 63;
    const int l15 = lane & 15;
    const int lg  = lane >> 4;                // 0..3
    const int rr  = lg;                       // staging row-within-4
    const int ch  = l15;                      // staging t-chunk (4 floats)
    const int k32_0 = ks * NKC;

    __shared__ float    Ls[2][32][65];        // raw fp32 x tiles (16.6KB)
    __shared__ _Float16 Bs[2][4][512];        // f16 B-fragments (8KB)

    const float* xn = x + (size_t)n * CHW * TT;
    const int toff = tb * 64 + ch * 4;        // t chunk base (float idx)
    const bool tbok = (tb < 7);               // tb==7: only ch<13 valid (t<500)

    f32x4 acc[2][4][2] = {};                  // [ofrag][tfrag][hl]
    f16x8 Ar0[2][2], Ar1[2][2];               // A dbuf [ofrag][hl]
    f32x4 sA[2], sB[2];                       // x staging reg sets (XG parity)
    const f32x4 f4z = {0.f, 0.f, 0.f, 0.f};

#define XG(set, it)                                                                \
    {                                                                              \
        _Pragma("unroll") for (int p_ = 0; p_ < 2; p_++) {                         \
            const int r_ = wave * 8 + p_ * 4 + rr;                                 \
            const int c_ = (k32_0 + (it)) * 32 + r_;                               \
            const bool v_ = (c_ < CHW) && (tbok || ch < 13);                       \
            set[p_] = v_ ? __builtin_nontemporal_load(                             \
                              (const f32x4*)(xn + (size_t)c_ * TT + toff))         \
                         : f4z;                                                    \
        }                                                                          \
    }

#define DSW(set, bufL)                                                             \
    {                                                                              \
        _Pragma("unroll") for (int p_ = 0; p_ < 2; p_++) {                         \
            const int r_ = wave * 8 + p_ * 4 + rr;                                 \
            Ls[bufL][r_][ch * 4 + 0] = set[p_][0];                                 \
            Ls[bufL][r_][ch * 4 + 1] = set[p_][1];                                 \
            Ls[bufL][r_][ch * 4 + 2] = set[p_][2];                                 \
            Ls[bufL][r_][ch * 4 + 3] = set[p_][3];                                 \
        }                                                                          \
    }

#define TRANS(bufL, bufB)                                                          \
    {                                                                              \
        float tv_[8];                                                              \
        _Pragma("unroll") for (int i = 0; i < 8; i++)                              \
            tv_[i] = Ls[bufL][lg * 8 + i][wave * 16 + l15];                        \
        union { _Float16 h[8]; uint4 u; } tc_;                                     \
        _Pragma("unroll") for (int i = 0; i < 8; i++)                              \
            tc_.h[i] = (_Float16)tv_[i];                                           \
        *(uint4*)&Bs[bufB][wave][lane * 8] = tc_.u;                                \
    }

// Direct-W fragment load + hi/lo split (bitwise same as packW path)
#define WLOAD(Ar, it)                                                              \
    {                                                                              \
        const int c_ = (k32_0 + (it)) * 32 + lg * 8;                               \
        _Pragma("unroll") for (int of = 0; of < 2; of++) {                         \
            const int o_ = (wave * 2 + of) * 16 + l15;                             \
            const float* wp_ = W + (size_t)o_ * CHW + c_;                          \
            float wv_[8];                                                          \
            if (c_ + 8 <= CHW) {                                                   \
                float4 a_ = *(const float4*)(wp_);                                 \
                float4 b_ = *(const float4*)(wp_ + 4);                             \
                wv_[0] = a_.x; wv_[1] = a_.y; wv_[2] = a_.z; wv_[3] = a_.w;        \
                wv_[4] = b_.x; wv_[5] = b_.y; wv_[6] = b_.z; wv_[7] = b_.w;        \
            } else {                                                               \
                _Pragma("unroll") for (int i = 0; i < 8; i++)                      \
                    wv_[i] = (c_ + i < CHW) ? wp_[i] : 0.f;                        \
            }                                                                      \
            union { _Float16 h[8]; f16x8 v; } hi_, lo_;                            \
            _Pragma("unroll") for (int i = 0; i < 8; i++) {                        \
                _Float16 h_ = (_Float16)wv_[i];                                    \
                hi_.h[i] = h_;                                                     \
                lo_.h[i] = (_Float16)((wv_[i] - (float)h_) * 2048.f);              \
            }                                                                      \
            Ar[of][0] = hi_.v;                                                     \
            Ar[of][1] = lo_.v;                                                     \
        }                                                                          \
    }

#define COMPUTE(buf, Ar)                                                           \
    {                                                                              \
        f16x8 bfr[4];                                                              \
        _Pragma("unroll") for (int tf = 0; tf < 4; tf++)                           \
            bfr[tf] = *(const f16x8*)&Bs[buf][tf][lane * 8];                       \
        _Pragma("unroll") for (int of = 0; of < 2; of++)                           \
            _Pragma("unroll") for (int tf = 0; tf < 4; tf++)                       \
                _Pragma("unroll") for (int hl = 0; hl < 2; hl++)                   \
                    acc[of][tf][hl] = __builtin_amdgcn_mfma_f32_16x16x32_f16(      \
                        Ar[of][hl], bfr[tf], acc[of][tf][hl], 0, 0, 0);            \
    }

    // prologue: tiles 0..3 in flight; Bs[0]=tile0, Ls[1]=tile1 ready after
    XG(sA, 0)
    XG(sB, 1)
    DSW(sA, 0)            // waits sA (one-time stall, counted)
    XG(sA, 2)
    wg_barrier_lgkm();    // Ls[0] (tile 0) visible
    TRANS(0, 0)           // Bs[0] = tile 0
    DSW(sB, 1)            // Ls[1] = tile 1
    XG(sB, 3)
    WLOAD(Ar0, 0)
    wg_barrier_lgkm();    // Bs[0], Ls[1] visible

    for (int p = 0; p < 12; ++p) {
        const int it = 2 * p;
        // even step (cur=0): sA carries tile it+2 -> Ls[0]; XG(it+4)->sA
        WLOAD(Ar1, it + 1)
        DSW(sA, 0)                       // tile it+2 (always valid: it<=22)
        if (p <= 10) { XG(sA, it + 4) }
        TRANS(1, 1)                      // Bs[1] = tile it+1
        COMPUTE(0, Ar0)
        wg_barrier_lgkm();
        // odd step (cur=1)
        WLOAD(Ar0, it + 2)
        if (p <= 10) { DSW(sB, 1) }      // tile it+3
        if (p <= 9)  { XG(sB, it + 5) }
        TRANS(0, 0)                      // Bs[0] = tile it+2
        COMPUTE(1, Ar1)
        wg_barrier_lgkm();
    }
    // tail: it = 24
    COMPUTE(0, Ar0)

    // epilogue: D layout col(l&15)=t, row=(l>>4)*4+r = o-within-frag
    const float inv = 1.f / 2048.f;
#pragma unroll
    for (int of = 0; of < 2; of++) {
        const int o0 = (wave * 2 + of) * 16 + lg * 4;
#pragma unroll
        for (int tf = 0; tf < 4; tf++) {
            const int t = tb * 64 + tf * 16 + l15;
            if (t < TT) {
                f32x4 vo;
#pragma unroll
                for (int r = 0; r < 4; r++)
                    vo[r] = acc[of][tf][0][r] + acc[of][tf][1][r] * inv;
                *(f32x4*)(vp + (((size_t)ks * TT + t) * NB + n) * OUT + o0) = vo;
            }
        }
    }
#undef XG
#undef DSW
#undef TRANS
#undef WLOAD
#undef COMPUTE
}

// ---------------- Kernel 2: wave-specialized alpha+spike scan, fused 8-partial ----
// 32 blocks x 512 thr, 32 chains/block. Wave 0 (lanes 0-31): serial G/H
// recursion; waves 1-7: stage next slab with the 8-partial K-sum fused.
#define SCN_RA 0.9048374180359595f       // exp(-0.1)
#define SCN_RACA 0.24596031111569496f    // RA*CA = 0.1*e^0.9
#define SCN_RS 0.36787944117144233f      // exp(-1)
#define SCN_RSCS -20.0f                  // RS*CS (CS = -20e)
#define SCN_RSCS2 -40.0f                 // 2*RS*CS
#define SCN_RSRSCS -7.3575888234288467f  // RS*RS*CS
#define SCN_TH 10.0f

#define CHAIN_STEP(i)                                                   \
    {                                                                   \
        float ua = Aa;                                                  \
        float w = fmaf(SCN_RS, G, ua);                                  \
        float u = sp ? (w + SCN_RSCS) : w;                              \
        bool sn = (u >= SCN_TH);                                        \
        sbuf[i][lane] = sn ? 1.f : 0.f;                                 \
        float Gb = fmaf(SCN_RS, G, H);                                  \
        G = sp ? (Gb + SCN_RSCS2) : Gb;                                 \
        float Hb = SCN_RS * H;                                          \
        H = sp ? (Hb + SCN_RSRSCS) : Hb;                                \
        sp = sn;                                                        \
        Ba = fmaf(SCN_RA, Ba, SCN_RACA * vv[i]);                        \
        Aa = fmaf(SCN_RA, Aa, Ba);                                      \
    }

__global__ __launch_bounds__(512) void scanspike(const float* __restrict__ vp,
                                                 float* __restrict__ out) {
    const int tid = threadIdx.x;
    const int wave = tid >> 6;
    const int lane = tid & 63;
    const int l5 = lane & 31;
    const int rh = lane >> 5;                // row-half within a pair
    const int g0 = blockIdx.x * 32;          // 32 chains per block
    const int cn = g0 >> 7;                  // n (fixed per block)
    const int co = (g0 & 127) + l5;          // o of this lane's chain

    __shared__ float vbuf[2][64][32];        // [buf][tloc][chain] 16KB
    __shared__ float sbuf[64][33];           // [tloc][chain+pad]

    for (int rp = wave; rp * 2 < 64; rp += 8) {
        int r = rp * 2 + rh;
        float a = 0.f;
#pragma unroll
        for (int k = 0; k < KSPLIT; k++)
            a += vp[(((size_t)k * TT + r) * NB + cn) * OUT + co];
        vbuf[0][r][l5] = a;
    }
    __syncthreads();

    float Aa = 0.f, Ba = 0.f, G = 0.f, H = 0.f;
    bool sp = false;

    for (int tb = 0; tb < 8; ++tb) {
        const int cur = tb & 1;
        const int t0 = tb * 64;
        const int cnt = (tb == 7) ? 52 : 64;

        if (wave == 0) {
            if (lane < 32) {
                if (cnt == 64) {
                    float vv[64];
#pragma unroll
                    for (int i = 0; i < 64; ++i) vv[i] = vbuf[cur][i][l5];
#pragma unroll
                    for (int i = 0; i < 64; ++i) CHAIN_STEP(i)
                } else {
                    float vv[52];
#pragma unroll
                    for (int i = 0; i < 52; ++i) vv[i] = vbuf[cur][i][l5];
#pragma unroll
                    for (int i = 0; i < 52; ++i) CHAIN_STEP(i)
                }
            }
        } else if (tb < 7) {
            const int nt0 = t0 + 64;
            const int ncnt = (tb == 6) ? 52 : 64;
            for (int rp = wave - 1; rp * 2 < ncnt; rp += 7) {
                int r = rp * 2 + rh;
                float a = 0.f;
#pragma unroll
                for (int k = 0; k < KSPLIT; k++)
                    a += vp[(((size_t)k * TT + nt0 + r) * NB + cn) * OUT + co];
                vbuf[cur ^ 1][r][l5] = a;
            }
        }
        __syncthreads();

#pragma unroll
        for (int j = 0; j < 4; ++j) {
            int cc = wave * 4 + j;
            int oo = (g0 & 127) + cc;
            if (lane < cnt)
                out[((size_t)cn * OUT + oo) * TT + t0 + lane] = sbuf[lane][cc];
        }
        __syncthreads();
    }
}

extern "C" void kernel_launch(void* const* d_in, const int* in_sizes, int n_in,
                              void* d_out, int out_size, void* d_ws, size_t ws_size,
                              hipStream_t stream) {
    const float* x = (const float*)d_in[0];   // [8,2,50,63,500] fp32
    const float* W = (const float*)d_in[1];   // [128,6300] fp32
    float* out = (float*)d_out;               // [8,128,1,1,500] fp32

    float* vp = (float*)d_ws;                 // 16,384,000 B partials

    gemm<<<512, 256, 0, stream>>>(x, W, vp);
    scanspike<<<32, 512, 0, stream>>>(vp, out);
}